// Round 6
// baseline (334.124 us; speedup 1.0000x reference)
//
#include <hip/hip_runtime.h>
#include <math.h>

// GHM-C loss, two-pass, LDS-histogram pass1.
// R3/R4 lessons: no grid-wide atomics (XCD funnel ~250us), no ballots
// (VALU->SALU hazards). R5 decomposition: harness floor ~138us, pass1 ~55us
// dominated by the 9x(cmp+cndmask+add+addc) nested-threshold chain.
// R6: compute bin = min(int(sigmoid(x)*10), 9) once per element (v_rcp based,
// ~1ulp; bin-boundary flips affect ~tens of 33.5M elements -> loss err <<1e-4)
// and accumulate (bce, 1) into a per-thread-column LDS histogram cell
// [bin][tid] via fire-and-forget ds_add atomics (uncontended by construction:
// each thread owns its column; stride 257 spreads banks). Block partials are
// direct per-bin sums/counts -> disjoint d_ws slots. Pass 2 (1 block)
// reduces and finalizes loss = sum_b S_b / (C_b * n_nonempty).

#define BLK 256
#define GRID 2048
#define BSTRIDE 257  // column stride in words (256 threads + 1 pad)

typedef float v4f __attribute__((ext_vector_type(4)));

__device__ __forceinline__ void wave_red(float& v) {
#pragma unroll
    for (int off = 32; off > 0; off >>= 1) v += __shfl_down(v, off, 64);
}

// Streaming element treated as non-target: s = x, g = sigmoid(x),
// bce = softplus(x). One sum-add and one count-add into this thread's column.
__device__ __forceinline__ void upd(float x, float* __restrict__ sSum,
                                    int* __restrict__ sCnt, int tid) {
    float a = fabsf(x);
    float en = __expf(-a);
    float den = 1.0f + en;
    float l1p = __logf(den);                     // log1p(exp(-|x|))
    float r = __builtin_amdgcn_rcpf(den);        // v_rcp_f32, ~1ulp
    float numer = (x >= 0.0f) ? 1.0f : en;
    float sig = numer * r;                       // sigmoid(x)
    int bin = (int)(sig * 10.0f);                // trunc, sig >= 0
    bin = bin > 9 ? 9 : bin;                     // g==1.0 -> last bin
    float bce = fmaxf(x, 0.0f) + l1p;            // softplus(x)
    atomicAdd(&sSum[bin * BSTRIDE + tid], bce);  // ds_add_f32, no-return
    atomicAdd(&sCnt[bin * BSTRIDE + tid], 1);    // ds_add_u32
}

// Target element with logit p: remove the s=p contribution added by the
// streaming loop, add the true target contribution (g = 1 - sigmoid(p),
// bce = softplus(-p)).
__device__ __forceinline__ void upd_corr(float p, float* __restrict__ sSum,
                                         int* __restrict__ sCnt, int tid) {
    float a = fabsf(p);
    float en = __expf(-a);
    float den = 1.0f + en;
    float l1p = __logf(den);
    float r = __builtin_amdgcn_rcpf(den);
    float numer = (p >= 0.0f) ? 1.0f : en;
    float sigp = numer * r;   // sigmoid(p) — identical to upd's computation
    float sigt = 1.0f - sigp; // g for the target case
    int bf = (int)(sigp * 10.0f);
    bf = bf > 9 ? 9 : bf;
    int bt = (int)(sigt * 10.0f);
    bt = bt > 9 ? 9 : bt;
    float bce_f = fmaxf(p, 0.0f) + l1p;   // remove
    float bce_t = fmaxf(-p, 0.0f) + l1p;  // add
    atomicAdd(&sSum[bf * BSTRIDE + tid], -bce_f);
    atomicAdd(&sCnt[bf * BSTRIDE + tid], -1);
    atomicAdd(&sSum[bt * BSTRIDE + tid], bce_t);
    atomicAdd(&sCnt[bt * BSTRIDE + tid], 1);
}

__global__ __launch_bounds__(BLK, 4) void ghmc_pass1(
    const float* __restrict__ pred, const int* __restrict__ target,
    float* __restrict__ blk, unsigned total4, unsigned totalNC, int N, int C) {
    __shared__ float sSum[10 * BSTRIDE];
    __shared__ int sCnt[10 * BSTRIDE];

    int tid = threadIdx.x;
    for (int i = tid; i < 10 * BSTRIDE; i += BLK) {
        sSum[i] = 0.0f;
        sCnt[i] = 0;
    }
    __syncthreads();

    unsigned gtid = blockIdx.x * BLK + tid;
    unsigned stride = gridDim.x * BLK;
    const v4f* p4 = (const v4f*)pred;

    // 2-wide unrolled grid-stride: two independent dwordx4 loads in flight
    unsigned v = gtid;
    for (; v + stride < total4; v += 2u * stride) {
        v4f a = p4[v];
        v4f b = p4[v + stride];
        upd(a[0], sSum, sCnt, tid);
        upd(a[1], sSum, sCnt, tid);
        upd(a[2], sSum, sCnt, tid);
        upd(a[3], sSum, sCnt, tid);
        upd(b[0], sSum, sCnt, tid);
        upd(b[1], sSum, sCnt, tid);
        upd(b[2], sSum, sCnt, tid);
        upd(b[3], sSum, sCnt, tid);
    }
    for (; v < total4; v += stride) {
        v4f a = p4[v];
        upd(a[0], sSum, sCnt, tid);
        upd(a[1], sSum, sCnt, tid);
        upd(a[2], sSum, sCnt, tid);
        upd(a[3], sSum, sCnt, tid);
    }

    // tail (NC % 4 != 0): global thread 0 only
    if (gtid == 0) {
        for (unsigned e = total4 << 2; e < totalNC; ++e)
            upd(pred[e], sSum, sCnt, tid);
    }

    // per-row target correction; each row handled exactly once. The element's
    // streaming contribution may have come from another block — per-block
    // partials can go negative; only the global sum matters (exact in int).
    if ((int)gtid < N) {
        int t = target[gtid];
        float p = pred[gtid * (unsigned)C + (unsigned)t];
        upd_corr(p, sSum, sCnt, tid);
    }

    __syncthreads();

    // block reduction: per bin, sum the 256 thread columns
    float vals[20];
#pragma unroll
    for (int b = 0; b < 10; ++b) {
        vals[b] = sSum[b * BSTRIDE + tid];
        vals[10 + b] = (float)sCnt[b * BSTRIDE + tid];
    }
#pragma unroll
    for (int i = 0; i < 20; ++i) wave_red(vals[i]);

    __shared__ float sW[BLK / 64][20];
    int wid = tid >> 6;
    int lane = tid & 63;
    if (lane == 0) {
#pragma unroll
        for (int i = 0; i < 20; ++i) sW[wid][i] = vals[i];
    }
    __syncthreads();
    if (tid == 0) {
        float* dst = blk + (unsigned)blockIdx.x * 20u;
#pragma unroll
        for (int i = 0; i < 20; ++i) {
            float acc = 0.0f;
            for (int w = 0; w < BLK / 64; ++w) acc += sW[w][i];
            dst[i] = acc;  // [0..9] per-bin bce sums, [10..19] per-bin counts
        }
    }
}

__global__ __launch_bounds__(256) void ghmc_pass2(
    const float* __restrict__ blk, float* __restrict__ out, int nblocks) {
    float P[20];
#pragma unroll
    for (int i = 0; i < 20; ++i) P[i] = 0.0f;

    for (int b = threadIdx.x; b < nblocks; b += 256) {
        const float* src = blk + (unsigned)b * 20u;
#pragma unroll
        for (int i = 0; i < 20; ++i) P[i] += src[i];
    }
#pragma unroll
    for (int i = 0; i < 20; ++i) wave_red(P[i]);

    __shared__ float sP[4][20];
    int wid = threadIdx.x >> 6;
    int lane = threadIdx.x & 63;
    if (lane == 0) {
#pragma unroll
        for (int i = 0; i < 20; ++i) sP[wid][i] = P[i];
    }
    __syncthreads();
    if (threadIdx.x == 0) {
#pragma unroll
        for (int i = 0; i < 20; ++i) {
            float a = 0.0f;
            for (int w = 0; w < 4; ++w) a += sP[w][i];
            P[i] = a;
        }
        // P[b] = S_b (bce sum in bin b), P[10+b] = C_b (count in bin b)
        int nonempty = 0;
        for (int b = 0; b < 10; ++b)
            if (P[10 + b] > 0.5f) nonempty++;
        float n = fmaxf((float)nonempty, 1.0f);

        float loss = 0.0f;
        for (int b = 0; b < 10; ++b) {
            if (P[10 + b] > 0.5f) loss += P[b] / (P[10 + b] * n);
        }
        out[0] = loss;  // LOSS_WEIGHT = 1.0
    }
}

extern "C" void kernel_launch(void* const* d_in, const int* in_sizes, int n_in,
                              void* d_out, int out_size, void* d_ws, size_t ws_size,
                              hipStream_t stream) {
    const float* pred = (const float*)d_in[0];
    const int* target = (const int*)d_in[1];
    int NC = in_sizes[0];
    int N = in_sizes[1];
    int C = NC / N;
    unsigned total4 = (unsigned)(NC / 4);

    int blocks = GRID;
    size_t per_block = 20 * sizeof(float);
    if (ws_size < (size_t)blocks * per_block) {
        size_t maxb = ws_size / per_block;
        blocks = (int)(maxb > 0 ? maxb : 1);
    }
    // per-row correction requires blocks*BLK >= N (2048*256 = 524288 >= 32768)

    float* blkbuf = (float*)d_ws;

    ghmc_pass1<<<blocks, BLK, 0, stream>>>(pred, target, blkbuf, total4,
                                           (unsigned)NC, N, C);
    ghmc_pass2<<<1, 256, 0, stream>>>(blkbuf, (float*)d_out, blocks);
}

// Round 7
// 216.194 us; speedup vs baseline: 1.5455x; 1.5455x over previous
//
#include <hip/hip_runtime.h>
#include <math.h>

// GHM-C loss, two-pass. Champion structure = R5 (201us total).
// Locked-in lessons: no grid-wide atomics (R4: ~250us XCD funnel), no
// ballots (R3: VALU->SALU hazard), no per-element LDS ops (R6: ds_add
// atomics ~80cyc effective -> 194us). Per-lane cmp+cndmask register chain
// is the right shape.
// R7 deltas vs R5: (1) software-pipelined loads (next dwordx4 pair in
// flight during compute -> hide ~900cyc HBM latency), (2) log1p(en) via
// deg-5 polynomial (A&S 4.1.44, |err|<1e-5) instead of v_log chain,
// (3) float4 partial reads in pass2.

#define BLK 256
#define GRID 2048

typedef float v4f __attribute__((ext_vector_type(4)));

__device__ __forceinline__ void wave_red(float& v) {
#pragma unroll
    for (int off = 32; off > 0; off >>= 1) v += __shfl_down(v, off, 64);
}
__device__ __forceinline__ void wave_red(int& v) {
#pragma unroll
    for (int off = 32; off > 0; off >>= 1) v += __shfl_down(v, off, 64);
}

// ln(1+t) on t in [0,1], |err| < 1e-5 (Abramowitz & Stegun 4.1.44).
__device__ __forceinline__ float log1p_poly(float t) {
    float r = 0.03215845f;
    r = fmaf(r, t, -0.13606275f);
    r = fmaf(r, t, 0.28947478f);
    r = fmaf(r, t, -0.49190896f);
    r = fmaf(r, t, 0.99949556f);
    return r * t;
}

__device__ __forceinline__ void upd(float x, float (&S)[10], int (&cnt)[9]) {
    // logit(k/10), k=1..9 — compile-time constants
    const float T0 = -2.1972246f, T1 = -1.3862944f, T2 = -0.84729786f,
                T3 = -0.40546511f, T4 = 0.0f, T5 = 0.40546511f,
                T6 = 0.84729786f, T7 = 1.3862944f, T8 = 2.1972246f;
    float en = __expf(-fabsf(x));           // v_mul(-|x|*log2e) + v_exp
    float bce = fmaxf(x, 0.0f) + log1p_poly(en);  // softplus(x)
    S[0] += bce;
    const float Tk[9] = {T0, T1, T2, T3, T4, T5, T6, T7, T8};
#pragma unroll
    for (int q = 0; q < 9; ++q) {
        bool b = (x >= Tk[q]);
        S[q + 1] += b ? bce : 0.0f;  // v_cmp + v_cndmask + v_add
        cnt[q] += b ? 1 : 0;         // carry-add off mask
    }
}

// Target element with logit p: remove the s=p contribution added by the
// streaming loop, add the true s=-p contribution. Uses the identical bce
// formula so the removal cancels the streamed value exactly.
__device__ __forceinline__ void upd_corr(float p, float (&S)[10], int (&cnt)[9]) {
    const float Tk[9] = {-2.1972246f, -1.3862944f, -0.84729786f, -0.40546511f,
                         0.0f, 0.40546511f, 0.84729786f, 1.3862944f, 2.1972246f};
    float en = __expf(-fabsf(p));
    float l1p = log1p_poly(en);
    float bf = fmaxf(p, 0.0f) + l1p;   // false contribution (remove)
    float bt = fmaxf(-p, 0.0f) + l1p;  // true contribution (add)
    S[0] += bt - bf;
#pragma unroll
    for (int q = 0; q < 9; ++q) {
        bool btq = (-p >= Tk[q]);
        bool bfq = (p >= Tk[q]);
        S[q + 1] += (btq ? bt : 0.0f) - (bfq ? bf : 0.0f);
        cnt[q] += (btq ? 1 : 0) - (bfq ? 1 : 0);
    }
}

__device__ __forceinline__ void upd4(const v4f& a, float (&S)[10], int (&cnt)[9]) {
    upd(a[0], S, cnt);
    upd(a[1], S, cnt);
    upd(a[2], S, cnt);
    upd(a[3], S, cnt);
}

__global__ __launch_bounds__(BLK, 8) void ghmc_pass1(
    const float* __restrict__ pred, const int* __restrict__ target,
    float* __restrict__ blk, unsigned total4, unsigned totalNC, int N, int C) {
    float S[10];
    int cnt[9];
#pragma unroll
    for (int i = 0; i < 10; ++i) S[i] = 0.0f;
#pragma unroll
    for (int i = 0; i < 9; ++i) cnt[i] = 0;

    unsigned gtid = blockIdx.x * BLK + threadIdx.x;
    unsigned stride = gridDim.x * BLK;
    const v4f* p4 = (const v4f*)pred;

    // software-pipelined pairs: next 2 dwordx4 in flight during compute
    unsigned v = gtid;
    if (v + stride < total4) {
        v4f a = p4[v];
        v4f b = p4[v + stride];
        unsigned nv = v + 2u * stride;
        while (nv + stride < total4) {
            v4f a2 = p4[nv];
            v4f b2 = p4[nv + stride];
            upd4(a, S, cnt);
            upd4(b, S, cnt);
            a = a2;
            b = b2;
            nv += 2u * stride;
        }
        upd4(a, S, cnt);
        upd4(b, S, cnt);
        v = nv;
    }
    for (; v < total4; v += stride) {
        v4f a = p4[v];
        upd4(a, S, cnt);
    }

    // tail (NC % 4 != 0): global thread 0 only
    if (gtid == 0) {
        for (unsigned e = total4 << 2; e < totalNC; ++e) upd(pred[e], S, cnt);
    }

    // per-row target correction; each row handled exactly once (per-block
    // partials may go negative; only the global sum matters)
    if ((int)gtid < N) {
        int t = target[gtid];
        float p = pred[gtid * (unsigned)C + (unsigned)t];
        upd_corr(p, S, cnt);
    }

    // block reduction
#pragma unroll
    for (int i = 0; i < 10; ++i) wave_red(S[i]);
#pragma unroll
    for (int i = 0; i < 9; ++i) wave_red(cnt[i]);

    __shared__ float sS[BLK / 64][10];
    __shared__ int sC[BLK / 64][9];
    int wid = threadIdx.x >> 6;
    int lane = threadIdx.x & 63;
    if (lane == 0) {
#pragma unroll
        for (int i = 0; i < 10; ++i) sS[wid][i] = S[i];
#pragma unroll
        for (int i = 0; i < 9; ++i) sC[wid][i] = cnt[i];
    }
    __syncthreads();
    if (threadIdx.x == 0) {
        const int nw = BLK / 64;
        float o[20];
#pragma unroll
        for (int i = 0; i < 10; ++i) {
            float a = 0.0f;
            for (int w = 0; w < nw; ++w) a += sS[w][i];
            o[i] = a;
        }
#pragma unroll
        for (int i = 0; i < 9; ++i) {
            int a = 0;
            for (int w = 0; w < nw; ++w) a += sC[w][i];
            o[10 + i] = (float)a;  // counts <= 524288, exact in fp32
        }
        o[19] = 0.0f;
        float* dst = blk + (unsigned)blockIdx.x * 20u;  // 80B slots, 16B-aligned
#pragma unroll
        for (int i = 0; i < 20; ++i) dst[i] = o[i];
    }
}

__global__ __launch_bounds__(256) void ghmc_pass2(
    const float* __restrict__ blk, float* __restrict__ out, int nblocks,
    float totalNC) {
    float P[20];
#pragma unroll
    for (int i = 0; i < 20; ++i) P[i] = 0.0f;

    const v4f* b4 = (const v4f*)blk;  // slot = 5 contiguous float4s
    for (int b = threadIdx.x; b < nblocks; b += 256) {
#pragma unroll
        for (int j = 0; j < 5; ++j) {
            v4f c = b4[b * 5 + j];
            P[4 * j + 0] += c[0];
            P[4 * j + 1] += c[1];
            P[4 * j + 2] += c[2];
            P[4 * j + 3] += c[3];
        }
    }
#pragma unroll
    for (int i = 0; i < 20; ++i) wave_red(P[i]);

    __shared__ float sP[4][20];
    int wid = threadIdx.x >> 6;
    int lane = threadIdx.x & 63;
    if (lane == 0) {
#pragma unroll
        for (int i = 0; i < 20; ++i) sP[wid][i] = P[i];
    }
    __syncthreads();
    if (threadIdx.x == 0) {
        float Sv[11], Cv[11];
        for (int i = 0; i < 20; ++i) {
            float a = 0.0f;
            for (int w = 0; w < 4; ++w) a += sP[w][i];
            P[i] = a;
        }
        for (int i = 0; i < 10; ++i) Sv[i] = P[i];
        Sv[10] = 0.0f;
        Cv[0] = totalNC;
        for (int i = 1; i < 10; ++i) Cv[i] = P[9 + i];
        Cv[10] = 0.0f;

        int nonempty = 0;
        for (int b = 0; b < 10; ++b)
            if (Cv[b] - Cv[b + 1] > 0.5f) nonempty++;
        float n = fmaxf((float)nonempty, 1.0f);

        float loss = 0.0f;
        for (int b = 0; b < 10; ++b) {
            float c = Cv[b] - Cv[b + 1];
            if (c > 0.5f) loss += (Sv[b] - Sv[b + 1]) / (c * n);
        }
        out[0] = loss;  // LOSS_WEIGHT = 1.0
    }
}

extern "C" void kernel_launch(void* const* d_in, const int* in_sizes, int n_in,
                              void* d_out, int out_size, void* d_ws, size_t ws_size,
                              hipStream_t stream) {
    const float* pred = (const float*)d_in[0];
    const int* target = (const int*)d_in[1];
    int NC = in_sizes[0];
    int N = in_sizes[1];
    int C = NC / N;
    unsigned total4 = (unsigned)(NC / 4);

    int blocks = GRID;
    size_t per_block = 20 * sizeof(float);
    if (ws_size < (size_t)blocks * per_block) {
        size_t maxb = ws_size / per_block;
        blocks = (int)(maxb > 0 ? maxb : 1);
    }
    // per-row correction requires blocks*BLK >= N (2048*256 = 524288 >= 32768)

    float* blkbuf = (float*)d_ws;

    ghmc_pass1<<<blocks, BLK, 0, stream>>>(pred, target, blkbuf, total4,
                                           (unsigned)NC, N, C);
    ghmc_pass2<<<1, 256, 0, stream>>>(blkbuf, (float*)d_out, blocks, (float)NC);
}

// Round 8
// 201.826 us; speedup vs baseline: 1.6555x; 1.0712x over previous
//
#include <hip/hip_runtime.h>
#include <math.h>

// GHM-C loss, two-pass. R5 champion structure (201us), single change in R8:
// __launch_bounds__(256,4) instead of (256,8).
// WHY: R3/R4 counters show the hot loop is ~90% VALU-issue-bound at ~50us,
// 2.5x the static instruction model. Their VGPR_Count=28 with 19 live
// accumulators means the (256,8) bound (512/8 = 64 unified regs/wave) forced
// accumulators into AGPRs -> v_accvgpr_read/write round-trip on every
// accumulator update (~3x instr on the 19 masked adds). 4 waves/EU is ample
// TLP for an issue-bound loop; 128 regs/wave removes the round-trips.
// Locked-in lessons: no grid-wide atomics (R4), no ballots (R3), no
// per-element LDS ops (R6), no sw-pipelining of this loop (R7).

#define BLK 256
#define GRID 2048

typedef float v4f __attribute__((ext_vector_type(4)));

// logit(k/10), k=1..9
__device__ __constant__ float kT[9] = {
    -2.1972246f, -1.3862944f, -0.84729786f, -0.40546511f, 0.0f,
    0.40546511f, 0.84729786f, 1.3862944f, 2.1972246f};

__device__ __forceinline__ void wave_red(float& v) {
#pragma unroll
    for (int off = 32; off > 0; off >>= 1) v += __shfl_down(v, off, 64);
}
__device__ __forceinline__ void wave_red(int& v) {
#pragma unroll
    for (int off = 32; off > 0; off >>= 1) v += __shfl_down(v, off, 64);
}

__device__ __forceinline__ void upd(float x, float (&S)[10], int (&cnt)[9]) {
    float en = __expf(-fabsf(x));
    float bce = fmaxf(x, 0.0f) + __logf(1.0f + en);  // softplus(x), stable
    S[0] += bce;
#pragma unroll
    for (int q = 0; q < 9; ++q) {
        bool b = (x >= kT[q]);
        S[q + 1] += b ? bce : 0.0f;  // v_cmp + v_cndmask + v_add
        cnt[q] += b ? 1 : 0;         // carry-add off mask
    }
}

// Target element with logit p: remove the s=p contribution added by the
// streaming loop, add the true s=-p contribution.
__device__ __forceinline__ void upd_corr(float p, float (&S)[10], int (&cnt)[9]) {
    float en = __expf(-fabsf(p));
    float l1p = __logf(1.0f + en);
    float bf = fmaxf(p, 0.0f) + l1p;   // false contribution (remove)
    float bt = fmaxf(-p, 0.0f) + l1p;  // true contribution (add)
    S[0] += bt - bf;
#pragma unroll
    for (int q = 0; q < 9; ++q) {
        bool btq = (-p >= kT[q]);
        bool bfq = (p >= kT[q]);
        S[q + 1] += (btq ? bt : 0.0f) - (bfq ? bf : 0.0f);
        cnt[q] += (btq ? 1 : 0) - (bfq ? 1 : 0);
    }
}

__global__ __launch_bounds__(BLK, 4) void ghmc_pass1(
    const float* __restrict__ pred, const int* __restrict__ target,
    float* __restrict__ blk, unsigned total4, unsigned totalNC, int N, int C) {
    float S[10];
    int cnt[9];
#pragma unroll
    for (int i = 0; i < 10; ++i) S[i] = 0.0f;
#pragma unroll
    for (int i = 0; i < 9; ++i) cnt[i] = 0;

    unsigned tid = blockIdx.x * blockDim.x + threadIdx.x;
    unsigned stride = gridDim.x * blockDim.x;
    const v4f* p4 = (const v4f*)pred;

    // 2-wide unrolled grid-stride: two independent dwordx4 loads in flight
    unsigned v = tid;
    for (; v + stride < total4; v += 2u * stride) {
        v4f a = p4[v];
        v4f b = p4[v + stride];
        upd(a[0], S, cnt);
        upd(a[1], S, cnt);
        upd(a[2], S, cnt);
        upd(a[3], S, cnt);
        upd(b[0], S, cnt);
        upd(b[1], S, cnt);
        upd(b[2], S, cnt);
        upd(b[3], S, cnt);
    }
    for (; v < total4; v += stride) {
        v4f a = p4[v];
        upd(a[0], S, cnt);
        upd(a[1], S, cnt);
        upd(a[2], S, cnt);
        upd(a[3], S, cnt);
    }

    // tail (NC % 4 != 0): global thread 0 only
    if (tid == 0) {
        for (unsigned e = total4 << 2; e < totalNC; ++e) upd(pred[e], S, cnt);
    }

    // per-row target correction; each row handled exactly once (per-block
    // partials may go negative; only the global sum matters)
    int row = (int)tid;
    if (row < N) {
        int t = target[row];
        float p = pred[(unsigned)row * (unsigned)C + (unsigned)t];
        upd_corr(p, S, cnt);
    }

    // block reduction
#pragma unroll
    for (int i = 0; i < 10; ++i) wave_red(S[i]);
#pragma unroll
    for (int i = 0; i < 9; ++i) wave_red(cnt[i]);

    __shared__ float sS[BLK / 64][10];
    __shared__ int sC[BLK / 64][9];
    int wid = threadIdx.x >> 6;
    int lane = threadIdx.x & 63;
    if (lane == 0) {
#pragma unroll
        for (int i = 0; i < 10; ++i) sS[wid][i] = S[i];
#pragma unroll
        for (int i = 0; i < 9; ++i) sC[wid][i] = cnt[i];
    }
    __syncthreads();
    if (threadIdx.x == 0) {
        const int nw = BLK / 64;
        float o[19];
#pragma unroll
        for (int i = 0; i < 10; ++i) {
            float a = 0.0f;
            for (int w = 0; w < nw; ++w) a += sS[w][i];
            o[i] = a;
        }
#pragma unroll
        for (int i = 0; i < 9; ++i) {
            int a = 0;
            for (int w = 0; w < nw; ++w) a += sC[w][i];
            o[10 + i] = (float)a;  // counts <= 524288, exact in fp32
        }
        float* dst = blk + (unsigned)blockIdx.x * 20u;  // 80B aligned slots
#pragma unroll
        for (int i = 0; i < 19; ++i) dst[i] = o[i];
    }
}

__global__ __launch_bounds__(256) void ghmc_pass2(
    const float* __restrict__ blk, float* __restrict__ out, int nblocks,
    float totalNC) {
    float P[19];
#pragma unroll
    for (int i = 0; i < 19; ++i) P[i] = 0.0f;

    for (int b = threadIdx.x; b < nblocks; b += 256) {
        const float* src = blk + (unsigned)b * 20u;
#pragma unroll
        for (int i = 0; i < 19; ++i) P[i] += src[i];
    }
#pragma unroll
    for (int i = 0; i < 19; ++i) wave_red(P[i]);

    __shared__ float sP[4][19];
    int wid = threadIdx.x >> 6;
    int lane = threadIdx.x & 63;
    if (lane == 0) {
#pragma unroll
        for (int i = 0; i < 19; ++i) sP[wid][i] = P[i];
    }
    __syncthreads();
    if (threadIdx.x == 0) {
        float Sv[11], Cv[11];
        for (int i = 0; i < 19; ++i) {
            float a = 0.0f;
            for (int w = 0; w < 4; ++w) a += sP[w][i];
            P[i] = a;
        }
        for (int i = 0; i < 10; ++i) Sv[i] = P[i];
        Sv[10] = 0.0f;
        Cv[0] = totalNC;
        for (int i = 1; i < 10; ++i) Cv[i] = P[9 + i];
        Cv[10] = 0.0f;

        int nonempty = 0;
        for (int b = 0; b < 10; ++b)
            if (Cv[b] - Cv[b + 1] > 0.5f) nonempty++;
        float n = fmaxf((float)nonempty, 1.0f);

        float loss = 0.0f;
        for (int b = 0; b < 10; ++b) {
            float c = Cv[b] - Cv[b + 1];
            if (c > 0.5f) loss += (Sv[b] - Sv[b + 1]) / (c * n);
        }
        out[0] = loss;  // LOSS_WEIGHT = 1.0
    }
}

extern "C" void kernel_launch(void* const* d_in, const int* in_sizes, int n_in,
                              void* d_out, int out_size, void* d_ws, size_t ws_size,
                              hipStream_t stream) {
    const float* pred = (const float*)d_in[0];
    const int* target = (const int*)d_in[1];
    int NC = in_sizes[0];
    int N = in_sizes[1];
    int C = NC / N;
    unsigned total4 = (unsigned)(NC / 4);

    int blocks = GRID;
    size_t per_block = 20 * sizeof(float);
    if (ws_size < (size_t)blocks * per_block) {
        size_t maxb = ws_size / per_block;
        blocks = (int)(maxb > 0 ? maxb : 1);
    }
    // per-row correction requires blocks*BLK >= N (2048*256 = 524288 >= 32768)

    float* blkbuf = (float*)d_ws;

    ghmc_pass1<<<blocks, BLK, 0, stream>>>(pred, target, blkbuf, total4,
                                           (unsigned)NC, N, C);
    ghmc_pass2<<<1, 256, 0, stream>>>(blkbuf, (float*)d_out, blocks, (float)NC);
}